// Round 6
// baseline (91273.517 us; speedup 1.0000x reference)
//
#include <hip/hip_runtime.h>

// ---------------------------------------------------------------------------
// DCRNN (2-layer DCGRU encoder) -- self-identifying, dtype-adaptive version.
// Rounds 1-5 all returned bit-exact-zero output; the only assumption common
// to all five was host-side d_in ordering/dtype. This version:
//   * maps inputs by in_sizes (host-readable), not by position
//   * disambiguates the three size-64 buffers (seq_lengths vs bc0/bc1) on
//     device by content (bc are exactly zero; seq_lengths words are >=1)
//   * detects bf16-vs-fp32 input encoding on device (S0 even-short exponent
//     test) and writes the output in the matching dtype
// Compute: one block per batch sample (64 blocks x 256 threads), full T=96
// x 2-layer recurrence in-block, heads fused. All internal math fp32.
// Thread mapping: tid = n*4 + g (n = node 0..63, g = feature quarter).
// LDS ~53.9 KB.
// ---------------------------------------------------------------------------

__device__ __forceinline__ float dcr_b2f(unsigned short x) {
  return __uint_as_float(((unsigned)x) << 16);
}
__device__ __forceinline__ unsigned short dcr_f2b(float x) {
  unsigned u = __float_as_uint(x);
  u += 0x7fffu + ((u >> 16) & 1u);
  return (unsigned short)(u >> 16);
}
__device__ __forceinline__ float dcr_ld(const void* p, int idx, int isf) {
  if (isf) return ((const float*)p)[idx];
  return dcr_b2f(((const unsigned short*)p)[idx]);
}
__device__ __forceinline__ float dcr_sigm(float x) {
  return 1.0f / (1.0f + __expf(-x));
}
__device__ __forceinline__ float dcr_tanh(float x) {
  return 2.0f / (1.0f + __expf(-2.0f * x)) - 1.0f;
}

// acc += x[k] * W[(fh+k)*5+m][cols]; W in original layout, either dtype.
// Gate (doG): 32 outputs (cols fb..fb+15, 64+fb..64+fb+15 of 128-wide rows).
// Cand (doC): 16 outputs (cols fb..fb+15 of 64-wide rows).
__device__ void dcr_proj(float* aG, float* aC, const float (*buf)[68],
                         const void* Wg, const void* Wc, int m, int fh,
                         int n, int fb, int doG, int doC, int isf) {
  if (!isf) {
    const unsigned* G = (const unsigned*)Wg;
    const unsigned* C = (const unsigned*)Wc;
    const int fd = fb >> 1;
    for (int k = 0; k < 64; ++k) {
      float xk = buf[n][k];
      int row = (fh + k) * 5 + m;
      if (doG) {
        const unsigned* wr = G + row * 64 + fd;
#pragma unroll
        for (int j = 0; j < 8; ++j) {
          unsigned p = wr[j];
          aG[j * 2]     += xk * __uint_as_float(p << 16);
          aG[j * 2 + 1] += xk * __uint_as_float(p & 0xFFFF0000u);
          unsigned p2 = wr[32 + j];
          aG[16 + j * 2]     += xk * __uint_as_float(p2 << 16);
          aG[16 + j * 2 + 1] += xk * __uint_as_float(p2 & 0xFFFF0000u);
        }
      }
      if (doC) {
        const unsigned* wr = C + row * 32 + fd;
#pragma unroll
        for (int j = 0; j < 8; ++j) {
          unsigned p = wr[j];
          aC[j * 2]     += xk * __uint_as_float(p << 16);
          aC[j * 2 + 1] += xk * __uint_as_float(p & 0xFFFF0000u);
        }
      }
    }
  } else {
    const float* G = (const float*)Wg;
    const float* C = (const float*)Wc;
    for (int k = 0; k < 64; ++k) {
      float xk = buf[n][k];
      int row = (fh + k) * 5 + m;
      if (doG) {
        const float* wr = G + row * 128 + fb;
#pragma unroll
        for (int j = 0; j < 16; ++j) {
          aG[j]      += xk * wr[j];
          aG[16 + j] += xk * wr[64 + j];
        }
      }
      if (doC) {
        const float* wr = C + row * 64 + fb;
#pragma unroll
        for (int j = 0; j < 16; ++j) aC[j] += xk * wr[j];
      }
    }
  }
}

// dst[n][fb..fb+15] = (cheb ? 2*(S@src) - dst : S@src); sS[n][m] bf16.
// In-place cheb touches only this thread's own dst elements (race-free).
__device__ void dcr_apply(float (*dst)[68], const float (*src)[68],
                          const unsigned short (*sS)[65], int n, int fb,
                          int cheb) {
  float acc[16];
#pragma unroll
  for (int j = 0; j < 16; ++j) acc[j] = 0.0f;
  for (int m = 0; m < 64; ++m) {
    float s = dcr_b2f(sS[n][m]);
    const float* sr = &src[m][fb];
    float4 v0 = *(const float4*)(sr);
    float4 v1 = *(const float4*)(sr + 4);
    float4 v2 = *(const float4*)(sr + 8);
    float4 v3 = *(const float4*)(sr + 12);
    acc[0]  += s * v0.x;  acc[1]  += s * v0.y;
    acc[2]  += s * v0.z;  acc[3]  += s * v0.w;
    acc[4]  += s * v1.x;  acc[5]  += s * v1.y;
    acc[6]  += s * v1.z;  acc[7]  += s * v1.w;
    acc[8]  += s * v2.x;  acc[9]  += s * v2.y;
    acc[10] += s * v2.z;  acc[11] += s * v2.w;
    acc[12] += s * v3.x;  acc[13] += s * v3.y;
    acc[14] += s * v3.z;  acc[15] += s * v3.w;
  }
  if (cheb) {
#pragma unroll
    for (int j = 0; j < 16; ++j) dst[n][fb + j] = 2.0f * acc[j] - dst[n][fb + j];
  } else {
#pragma unroll
    for (int j = 0; j < 16; ++j) dst[n][fb + j] = acc[j];
  }
}

// One 64-feature half of the diffusion conv (input staged in xa, barrier
// done). Terms: x -> t1=S0@x (xb) -> t2=2*S0@t1-x (xa, in place) ->
// t3=S1@t1 (xa) -> t4=2*S1@t3-t1 (xb, in place). Projections of all 5.
__device__ void dcr_half(float* aG, float* aC, const void* Wg, const void* Wc,
                         int fh, int doG, int doC,
                         float (*xa)[68], float (*xb)[68],
                         const unsigned short (*sS0)[65],
                         const unsigned short (*sS1)[65],
                         int n, int fb, int isf) {
  dcr_proj(aG, aC, xa, Wg, Wc, 0, fh, n, fb, doG, doC, isf);
  dcr_apply(xb, xa, sS0, n, fb, 0);
  __syncthreads();
  dcr_proj(aG, aC, xb, Wg, Wc, 1, fh, n, fb, doG, doC, isf);
  dcr_apply(xa, xb, sS0, n, fb, 1);
  __syncthreads();
  dcr_proj(aG, aC, xa, Wg, Wc, 2, fh, n, fb, doG, doC, isf);
  __syncthreads();
  dcr_apply(xa, xb, sS1, n, fb, 0);
  __syncthreads();
  dcr_proj(aG, aC, xa, Wg, Wc, 3, fh, n, fb, doG, doC, isf);
  dcr_apply(xb, xa, sS1, n, fb, 1);
  __syncthreads();
  dcr_proj(aG, aC, xb, Wg, Wc, 4, fh, n, fb, doG, doC, isf);
  __syncthreads();
}

__global__ __launch_bounds__(256) void dcr_main(
    const void* xseq, const void* s0, const void* s1,
    const void* wg0, const void* wc0, const void* wg1, const void* wc1,
    const void* bg0, const void* bg1,
    const void* p64a, const void* p64b, const void* p64c,
    const void* fcw, const void* fcb, const void* idw, const void* idb,
    void* outp) {
  __shared__ float xa[64][68];
  __shared__ float xb[64][68];
  __shared__ unsigned short sS[2][64][65];
  __shared__ float bGs[2][128];
  __shared__ float bCs[2][64];
  __shared__ float red[4][54];
  __shared__ int ctl[4];

  const int tid = threadIdx.x;
  const int b = blockIdx.x;
  const int n = tid >> 2;
  const int fb = (tid & 3) * 16;

  // ---- on-device identification: dtype, seq-vs-bc, int width ----
  if (tid == 0) {
    // dtype: bf16 buffers have even-index shorts = values (high byte in
    // [0x30,0x3F] for small positives); fp32 buffers have mantissa junk there.
    const unsigned short* ss = (const unsigned short*)s0;
    int hits = 0;
    for (int i = 0; i < 32; ++i) {
      unsigned hb = ((unsigned)ss[2 * i] >> 8) & 0xFFu;
      if (hb >= 0x30u && hb <= 0x3Fu) ++hits;
    }
    int isf = (hits < 16) ? 1 : 0;
    // seq_lengths: the size-64 buffer with nonzero content (bc are zeros)
    const void* cand0 = p64a;
    const void* cand1 = p64b;
    const void* cand2 = p64c;
    int sel = 0;
    {
      const unsigned* w = (const unsigned*)cand0;
      unsigned any = 0;
      for (int i = 0; i < 16; ++i) any |= w[i];
      if (!any) {
        sel = 1;
        const unsigned* w1 = (const unsigned*)cand1;
        unsigned any1 = 0;
        for (int i = 0; i < 16; ++i) any1 |= w1[i];
        if (!any1) sel = 2;
      }
    }
    const unsigned* w = (const unsigned*)(sel == 0 ? cand0 : (sel == 1 ? cand1 : cand2));
    int i64 = 1;
    for (int i = 0; i < 8; ++i)
      if (w[2 * i + 1] != 0u) i64 = 0;
    ctl[0] = isf;
    ctl[1] = sel;
    ctl[2] = i64;
  }
  __syncthreads();
  const int isf = ctl[0];
  const int sel = ctl[1];
  const int i64 = ctl[2];
  const void* seqp = (sel == 0) ? p64a : (sel == 1 ? p64b : p64c);
  const void* bcA  = (sel == 0) ? p64b : p64a;   // first remaining -> bc0
  const void* bcB  = (sel == 2) ? p64b : p64c;   // second remaining -> bc1

  // ---- stage supports (as bf16) and biases ----
  for (int i = 0; i < 16; ++i) {
    int flat = i * 256 + tid;  // 0..4095
    int nn = flat >> 6, mm = flat & 63;
    unsigned short v0, v1;
    if (isf) {
      v0 = dcr_f2b(((const float*)s0)[flat]);
      v1 = dcr_f2b(((const float*)s1)[flat]);
    } else {
      v0 = ((const unsigned short*)s0)[flat];
      v1 = ((const unsigned short*)s1)[flat];
    }
    sS[0][nn][mm] = v0;
    sS[1][nn][mm] = v1;
  }
  if (tid < 128) {
    bGs[0][tid] = dcr_ld(bg0, tid, isf);
    bGs[1][tid] = dcr_ld(bg1, tid, isf);
  } else if (tid < 192) {
    int j = tid - 128;
    bCs[0][j] = dcr_ld(bcA, j, isf);
    bCs[1][j] = dcr_ld(bcB, j, isf);
  }

  int tl;
  if (i64) tl = (int)((const long long*)seqp)[b] - 1;
  else     tl = ((const int*)seqp)[b] - 1;
  if (tl < 0) tl = 0;
  if (tl > 95) tl = 95;

  float h0r[16], h1r[16];
#pragma unroll
  for (int j = 0; j < 16; ++j) { h0r[j] = 0.0f; h1r[j] = 0.0f; }
  __syncthreads();

  for (int t = 0; t < 96; ++t) {
    // ================= layer 0 (x from global) =================
    {
      float aG[32], aC[16];
#pragma unroll
      for (int j = 0; j < 32; ++j) aG[j] = 0.0f;
#pragma unroll
      for (int j = 0; j < 16; ++j) aC[j] = 0.0f;
      int xoff = (b * 96 + t) * 4096 + n * 64 + fb;
#pragma unroll
      for (int j = 0; j < 16; ++j) xa[n][fb + j] = dcr_ld(xseq, xoff + j, isf);
      __syncthreads();
      dcr_half(aG, aC, wg0, wc0, 0, 1, 1, xa, xb, sS[0], sS[1], n, fb, isf);
#pragma unroll
      for (int j = 0; j < 16; ++j) xa[n][fb + j] = h0r[j];
      __syncthreads();
      dcr_half(aG, aC, wg0, wc0, 64, 1, 0, xa, xb, sS[0], sS[1], n, fb, isf);
      float rr[16], uu[16];
#pragma unroll
      for (int j = 0; j < 16; ++j) {
        rr[j] = dcr_sigm(aG[j] + bGs[0][fb + j]);
        uu[j] = dcr_sigm(aG[16 + j] + bGs[0][64 + fb + j]);
      }
#pragma unroll
      for (int j = 0; j < 16; ++j) xa[n][fb + j] = rr[j] * h0r[j];
      __syncthreads();
      dcr_half(aG, aC, wg0, wc0, 64, 0, 1, xa, xb, sS[0], sS[1], n, fb, isf);
#pragma unroll
      for (int j = 0; j < 16; ++j) {
        float c = dcr_tanh(aC[j] + bCs[0][fb + j]);
        h0r[j] = uu[j] * h0r[j] + (1.0f - uu[j]) * c;
      }
    }
    // ================= layer 1 (x = h0) =================
    {
      float aG[32], aC[16];
#pragma unroll
      for (int j = 0; j < 32; ++j) aG[j] = 0.0f;
#pragma unroll
      for (int j = 0; j < 16; ++j) aC[j] = 0.0f;
#pragma unroll
      for (int j = 0; j < 16; ++j) xa[n][fb + j] = h0r[j];
      __syncthreads();
      dcr_half(aG, aC, wg1, wc1, 0, 1, 1, xa, xb, sS[0], sS[1], n, fb, isf);
#pragma unroll
      for (int j = 0; j < 16; ++j) xa[n][fb + j] = h1r[j];
      __syncthreads();
      dcr_half(aG, aC, wg1, wc1, 64, 1, 0, xa, xb, sS[0], sS[1], n, fb, isf);
      float rr[16], uu[16];
#pragma unroll
      for (int j = 0; j < 16; ++j) {
        rr[j] = dcr_sigm(aG[j] + bGs[1][fb + j]);
        uu[j] = dcr_sigm(aG[16 + j] + bGs[1][64 + fb + j]);
      }
#pragma unroll
      for (int j = 0; j < 16; ++j) xa[n][fb + j] = rr[j] * h1r[j];
      __syncthreads();
      dcr_half(aG, aC, wg1, wc1, 64, 0, 1, xa, xb, sS[0], sS[1], n, fb, isf);
#pragma unroll
      for (int j = 0; j < 16; ++j) {
        float c = dcr_tanh(aC[j] + bCs[1][fb + j]);
        h1r[j] = uu[j] * h1r[j] + (1.0f - uu[j]) * c;
      }
    }
    if (t == tl) break;
  }

  // ================= heads: relu -> fc/id matmul -> max over nodes ==========
  __syncthreads();
#pragma unroll
  for (int j = 0; j < 16; ++j) xa[n][fb + j] = fmaxf(h1r[j], 0.0f);
  {
    int u = tid >> 2;
    for (int c = (tid & 3); c < 54; c += 4)
      xb[u][c] = (c < 4) ? dcr_ld(fcw, u * 4 + c, isf)
                         : dcr_ld(idw, u * 50 + (c - 4), isf);
  }
  __syncthreads();
  if (tid < 216) {
    int c = tid % 54, nb = tid / 54;
    float mx = -3.4e38f;
    for (int nn = nb * 16; nn < nb * 16 + 16; ++nn) {
      float s = 0.0f;
#pragma unroll 8
      for (int u = 0; u < 64; ++u) s += xa[nn][u] * xb[u][c];
      mx = fmaxf(mx, s);
    }
    red[nb][c] = mx;
  }
  __syncthreads();
  if (tid < 54) {
    float mx = fmaxf(fmaxf(red[0][tid], red[1][tid]),
                     fmaxf(red[2][tid], red[3][tid]));
    mx += (tid < 4) ? dcr_ld(fcb, tid, isf) : dcr_ld(idb, tid - 4, isf);
    int o = (tid < 4) ? (b * 4 + tid) : (256 + b * 50 + (tid - 4));
    if (isf) ((float*)outp)[o] = mx;
    else     ((unsigned short*)outp)[o] = dcr_f2b(mx);
  }
}

static int dcr_find_nth(const int* s, int n, int sz, int nth) {
  int c = 0;
  for (int i = 0; i < n; ++i)
    if (s[i] == sz) { if (c == nth) return i; ++c; }
  return -1;
}

extern "C" void kernel_launch(void* const* d_in, const int* in_sizes, int n_in,
                              void* d_out, int out_size, void* d_ws, size_t ws_size,
                              hipStream_t stream) {
  (void)out_size; (void)d_ws; (void)ws_size;
  // Identify inputs by element count (order-invariant); fall back to the
  // setup_inputs() dict order if any lookup fails.
  int i_seq = dcr_find_nth(in_sizes, n_in, 393216, 0);
  int i_s0  = dcr_find_nth(in_sizes, n_in, 4096, 0);
  int i_s1  = dcr_find_nth(in_sizes, n_in, 4096, 1);
  int i_wg0 = dcr_find_nth(in_sizes, n_in, 81920, 0);
  int i_wg1 = dcr_find_nth(in_sizes, n_in, 81920, 1);
  int i_wc0 = dcr_find_nth(in_sizes, n_in, 40960, 0);
  int i_wc1 = dcr_find_nth(in_sizes, n_in, 40960, 1);
  int i_bg0 = dcr_find_nth(in_sizes, n_in, 128, 0);
  int i_bg1 = dcr_find_nth(in_sizes, n_in, 128, 1);
  int i_64a = dcr_find_nth(in_sizes, n_in, 64, 0);
  int i_64b = dcr_find_nth(in_sizes, n_in, 64, 1);
  int i_64c = dcr_find_nth(in_sizes, n_in, 64, 2);
  int i_fcw = dcr_find_nth(in_sizes, n_in, 256, 0);
  int i_fcb = dcr_find_nth(in_sizes, n_in, 4, 0);
  int i_idw = dcr_find_nth(in_sizes, n_in, 3200, 0);
  int i_idb = dcr_find_nth(in_sizes, n_in, 50, 0);
  if (i_seq < 0 || i_s0 < 0 || i_s1 < 0 || i_wg0 < 0 || i_wg1 < 0 ||
      i_wc0 < 0 || i_wc1 < 0 || i_bg0 < 0 || i_bg1 < 0 || i_64a < 0 ||
      i_64b < 0 || i_64c < 0 || i_fcw < 0 || i_fcb < 0 || i_idw < 0 ||
      i_idb < 0) {
    i_seq = 0;  i_64a = 1;  i_s0 = 2;   i_s1 = 3;
    i_wg0 = 4;  i_bg0 = 5;  i_wc0 = 6;  i_64b = 7;
    i_wg1 = 8;  i_bg1 = 9;  i_wc1 = 10; i_64c = 11;
    i_fcw = 12; i_fcb = 13; i_idw = 14; i_idb = 15;
  }

  dcr_main<<<dim3(64), dim3(256), 0, stream>>>(
      d_in[i_seq], d_in[i_s0], d_in[i_s1],
      d_in[i_wg0], d_in[i_wc0], d_in[i_wg1], d_in[i_wc1],
      d_in[i_bg0], d_in[i_bg1],
      d_in[i_64a], d_in[i_64b], d_in[i_64c],
      d_in[i_fcw], d_in[i_fcb], d_in[i_idw], d_in[i_idb],
      d_out);
}